// Round 7
// baseline (668.438 us; speedup 1.0000x reference)
//
#include <hip/hip_runtime.h>
#include <cstdint>
#include <cstddef>

#define E_DIM 512
#define H_DIM 512
#define V_DIM 32000
#define B_DIM 64
#define T_DIM 20
#define NBLK_LSTM 128

typedef _Float16 f16;
typedef _Float16 f16x8 __attribute__((ext_vector_type(8)));
typedef _Float16 f16x4 __attribute__((ext_vector_type(4)));
typedef float    f32x4 __attribute__((ext_vector_type(4)));

__device__ __forceinline__ void async_lds16(void* lds, const void* g) {
  __builtin_amdgcn_global_load_lds(
      (const __attribute__((address_space(1))) uint32_t*)g,
      (__attribute__((address_space(3))) uint32_t*)lds, 16, 0, 0);
}

__device__ __forceinline__ float sigmoidf_(float x) {
  return 1.0f / (1.0f + expf(-x));
}

// ---------------------------------------------------------------------------
// Gather x rows to fp16: x16[m][512], m = b*21+t; rows 1344..1407 zero pad.
// ---------------------------------------------------------------------------
__global__ __launch_bounds__(128) void gather_x16_kernel(
    const float* __restrict__ features, const int* __restrict__ captions,
    const float* __restrict__ emb, f16* __restrict__ x16) {
  const int m = blockIdx.x;
  const int j = threadIdx.x;
  f16x4 r4 = {(f16)0.f, (f16)0.f, (f16)0.f, (f16)0.f};
  if (m < 1344) {
    const int b = m / 21;
    const int t = m % 21;
    const float* src = (t == 0)
        ? features + (size_t)b * E_DIM
        : emb + (size_t)captions[b * T_DIM + (t - 1)] * E_DIM;
    const float4 v = ((const float4*)src)[j];
    r4.x = (f16)v.x; r4.y = (f16)v.y; r4.z = (f16)v.z; r4.w = (f16)v.w;
  }
  ((f16x4*)(x16 + (size_t)m * 512))[j] = r4;
}

__global__ __launch_bounds__(256) void convert_w_kernel(
    const float* __restrict__ w, f16* __restrict__ w16) {
  const int i = blockIdx.x * 256 + threadIdx.x;
  const float4 v = ((const float4*)w)[i];
  f16x4 r;
  r.x = (f16)v.x; r.y = (f16)v.y; r.z = (f16)v.z; r.w = (f16)v.w;
  ((f16x4*)w16)[i] = r;
}

__global__ __launch_bounds__(256) void bias_sum_kernel(
    const float* __restrict__ a, const float* __restrict__ b,
    float* __restrict__ o) {
  const int i = blockIdx.x * 256 + threadIdx.x;
  if (i < 2048) o[i] = a[i] + b[i];
}

// ---------------------------------------------------------------------------
// K=512 fp16 GEMM (B^T form): C = A.Bw^T + bias. 128x128 tile, BK=64,
// 4 waves (2x2), 16x16x32 f16 MFMA, global_load_lds. f32-C variant.
// ---------------------------------------------------------------------------
__global__ __launch_bounds__(256) void gemm16_kernel(
    const f16* __restrict__ A, const f16* __restrict__ Bw,
    const float* __restrict__ bias, float* __restrict__ C, int ldc) {
  __shared__ f16 As[128 * 64];
  __shared__ f16 Bs[128 * 64];
  const int tid = threadIdx.x;
  const int lane = tid & 63;
  const int wid = tid >> 6;
  const int m0 = blockIdx.y * 128;
  const int n0 = blockIdx.x * 128;
  const int wm = (wid >> 1) * 64;
  const int wn = (wid & 1) * 64;

  f32x4 acc[4][4];
#pragma unroll
  for (int i = 0; i < 4; ++i)
#pragma unroll
    for (int j = 0; j < 4; ++j) {
      f32x4 z = {0.f, 0.f, 0.f, 0.f};
      acc[i][j] = z;
    }
  const int lr = lane & 15;
  const int lkb = (lane >> 4) * 8;

  for (int kt = 0; kt < 512; kt += 64) {
#pragma unroll
    for (int i = 0; i < 4; ++i) {
      const int off = i * 4096 + wid * 1024 + lane * 16;
      const int row = off >> 7;
      const int colh = (off & 127) >> 1;
      async_lds16((char*)As + i * 4096 + wid * 1024,
                  A + (size_t)(m0 + row) * 512 + kt + colh);
      async_lds16((char*)Bs + i * 4096 + wid * 1024,
                  Bw + (size_t)(n0 + row) * 512 + kt + colh);
    }
    __syncthreads();
#pragma unroll
    for (int ks = 0; ks < 2; ++ks) {
      f16x8 af[4], bf[4];
#pragma unroll
      for (int mi = 0; mi < 4; ++mi)
        af[mi] = *(const f16x8*)&As[(wm + mi * 16 + lr) * 64 + ks * 32 + lkb];
#pragma unroll
      for (int ni = 0; ni < 4; ++ni)
        bf[ni] = *(const f16x8*)&Bs[(wn + ni * 16 + lr) * 64 + ks * 32 + lkb];
#pragma unroll
      for (int mi = 0; mi < 4; ++mi)
#pragma unroll
        for (int ni = 0; ni < 4; ++ni)
          acc[mi][ni] = __builtin_amdgcn_mfma_f32_16x16x32_f16(
              af[mi], bf[ni], acc[mi][ni], 0, 0, 0);
    }
    __syncthreads();
  }

#pragma unroll
  for (int mi = 0; mi < 4; ++mi) {
    const int mbase = m0 + wm + mi * 16 + (lane >> 4) * 4;
#pragma unroll
    for (int ni = 0; ni < 4; ++ni) {
      const int n = n0 + wn + ni * 16 + lr;
      const float bv = bias[n];
#pragma unroll
      for (int r = 0; r < 4; ++r)
        C[(size_t)(mbase + r) * ldc + n] = acc[mi][ni][r] + bv;
    }
  }
}

// Same GEMM, f16 C output (halves logit-write traffic). ldc fixed 32000.
__global__ __launch_bounds__(256) void gemm16_f16out_kernel(
    const f16* __restrict__ A, const f16* __restrict__ Bw,
    const float* __restrict__ bias, f16* __restrict__ C16) {
  __shared__ f16 As[128 * 64];
  __shared__ f16 Bs[128 * 64];
  const int tid = threadIdx.x;
  const int lane = tid & 63;
  const int wid = tid >> 6;
  const int m0 = blockIdx.y * 128;
  const int n0 = blockIdx.x * 128;
  const int wm = (wid >> 1) * 64;
  const int wn = (wid & 1) * 64;

  f32x4 acc[4][4];
#pragma unroll
  for (int i = 0; i < 4; ++i)
#pragma unroll
    for (int j = 0; j < 4; ++j) {
      f32x4 z = {0.f, 0.f, 0.f, 0.f};
      acc[i][j] = z;
    }
  const int lr = lane & 15;
  const int lkb = (lane >> 4) * 8;

  for (int kt = 0; kt < 512; kt += 64) {
#pragma unroll
    for (int i = 0; i < 4; ++i) {
      const int off = i * 4096 + wid * 1024 + lane * 16;
      const int row = off >> 7;
      const int colh = (off & 127) >> 1;
      async_lds16((char*)As + i * 4096 + wid * 1024,
                  A + (size_t)(m0 + row) * 512 + kt + colh);
      async_lds16((char*)Bs + i * 4096 + wid * 1024,
                  Bw + (size_t)(n0 + row) * 512 + kt + colh);
    }
    __syncthreads();
#pragma unroll
    for (int ks = 0; ks < 2; ++ks) {
      f16x8 af[4], bf[4];
#pragma unroll
      for (int mi = 0; mi < 4; ++mi)
        af[mi] = *(const f16x8*)&As[(wm + mi * 16 + lr) * 64 + ks * 32 + lkb];
#pragma unroll
      for (int ni = 0; ni < 4; ++ni)
        bf[ni] = *(const f16x8*)&Bs[(wn + ni * 16 + lr) * 64 + ks * 32 + lkb];
#pragma unroll
      for (int mi = 0; mi < 4; ++mi)
#pragma unroll
        for (int ni = 0; ni < 4; ++ni)
          acc[mi][ni] = __builtin_amdgcn_mfma_f32_16x16x32_f16(
              af[mi], bf[ni], acc[mi][ni], 0, 0, 0);
    }
    __syncthreads();
  }

#pragma unroll
  for (int mi = 0; mi < 4; ++mi) {
    const int mbase = m0 + wm + mi * 16 + (lane >> 4) * 4;
#pragma unroll
    for (int ni = 0; ni < 4; ++ni) {
      const int n = n0 + wn + ni * 16 + lr;
      const float bv = bias[n];
#pragma unroll
      for (int r = 0; r < 4; ++r)
        C16[(size_t)(mbase + r) * 32000 + n] = (f16)(acc[mi][ni][r] + bv);
    }
  }
}

// ---------------------------------------------------------------------------
// Persistent LSTM: ONE kernel, 21 steps, device-scope grid barrier.
// 128 blocks x 256 thr; block owns u0=blk*4 h-units; wave = 16 b-rows.
// wS (w_hh slice) staged ONCE; c in registers; h ping-pong in global f16.
// Step 0: h=0 -> gates = P only (no MFMA). Barrier after steps 0..19.
// Co-residency: 128 blocks <= 256 CUs at 1 block/CU (83KB LDS) -> no deadlock.
// ---------------------------------------------------------------------------
__global__ __launch_bounds__(256) void lstm_persistent(
    const float* __restrict__ P, const f16* __restrict__ Whh,
    f16* __restrict__ hA, f16* __restrict__ hB,
    f16* __restrict__ hs16, unsigned* __restrict__ bar) {
  __shared__ f16 hS[64 * 520];
  __shared__ f16 wS[16 * 520];
  const int tid = threadIdx.x;
  const int lane = tid & 63;
  const int w = tid >> 6;
  const int u0 = blockIdx.x * 4;

  // stage w_hh slice once: rows rr=g*4+j <-> Whh row g*512+u0+j
  for (int i = tid; i < 1024; i += 256) {
    const int rr = i >> 6;
    const int cc = (i & 63) * 8;
    const int g = rr >> 2, j = rr & 3;
    *(f16x8*)&wS[rr * 520 + cc] =
        *(const f16x8*)&Whh[((size_t)(g * 512 + u0 + j)) * 512 + cc];
  }
  __syncthreads();

  const int fr = lane & 15;
  const int fq = lane >> 4;
  const int grow = (fr >> 2) * 512 + u0 + (fr & 3);
  float cr[4] = {0.f, 0.f, 0.f, 0.f};   // c for (b=w*16+fq*4+r, u=u0+fr), fr<4

  for (int t = 0; t <= T_DIM; ++t) {
    f32x4 acc = {0.f, 0.f, 0.f, 0.f};
    if (t > 0) {
      // stage this wave's 16 h rows from ping-pong buffer (wave-local LDS)
      const f16* hin = (t & 1) ? hA : hB;
      for (int i = lane; i < 1024; i += 64) {
        const int r = i >> 6;
        const int cc = (i & 63) * 8;
        *(f16x8*)&hS[(w * 16 + r) * 520 + cc] =
            *(const f16x8*)&hin[(size_t)(w * 16 + r) * 512 + cc];
      }
#pragma unroll
      for (int kk = 0; kk < 16; ++kk) {
        const int kc = kk * 32 + fq * 8;
        const f16x8 a = *(const f16x8*)&hS[(w * 16 + fr) * 520 + kc];
        const f16x8 b = *(const f16x8*)&wS[fr * 520 + kc];
        acc = __builtin_amdgcn_mfma_f32_16x16x32_f16(a, b, acc, 0, 0, 0);
      }
    }
    // add P; P row m = b*21 + t
#pragma unroll
    for (int r = 0; r < 4; ++r) {
      const int b = w * 16 + fq * 4 + r;
      acc[r] += P[((size_t)b * 21 + t) * 2048 + grow];
    }
    // gather gates i,f,g,o (lanes fr, fr^4, fr^8, fr^12) and apply
    f16* hout = (t & 1) ? hB : hA;
#pragma unroll
    for (int r = 0; r < 4; ++r) {
      const float x  = acc[r];
      const float xf = __shfl_xor(x, 4);
      const float xg = __shfl_xor(x, 8);
      const float xo = __shfl_xor(x, 12);
      if (fr < 4) {
        const int b = w * 16 + fq * 4 + r;
        const int u = u0 + fr;
        const float si = sigmoidf_(x);
        const float sf = sigmoidf_(xf);
        const float tg = tanhf(xg);
        const float so = sigmoidf_(xo);
        const float cn = sf * cr[r] + si * tg;
        cr[r] = cn;
        const float hn = so * tanhf(cn);
        hout[(size_t)b * 512 + u] = (f16)hn;
        if (t >= 1)
          hs16[((size_t)b * T_DIM + (t - 1)) * 512 + u] = (f16)hn;
      }
    }
    if (t < T_DIM) {
      // device-scope barrier: all h stores visible before any block proceeds
      __threadfence();
      __syncthreads();
      if (tid == 0) {
        __hip_atomic_fetch_add(bar, 1u, __ATOMIC_RELEASE,
                               __HIP_MEMORY_SCOPE_AGENT);
        const unsigned target = (unsigned)(NBLK_LSTM * (t + 1));
        while (__hip_atomic_load(bar, __ATOMIC_ACQUIRE,
                                 __HIP_MEMORY_SCOPE_AGENT) < target)
          __builtin_amdgcn_s_sleep(1);
      }
      __syncthreads();
    }
  }
}

// ---------------------------------------------------------------------------
// Softmax over V=32000, row in registers. f16-logit input variant (reads lg,
// writes f32 out) and f32 in-place fallback. One block (1024 thr) per row.
// ---------------------------------------------------------------------------
__device__ __forceinline__ float waveMax(float v) {
#pragma unroll
  for (int o = 32; o > 0; o >>= 1) v = fmaxf(v, __shfl_down(v, o));
  return v;
}
__device__ __forceinline__ float waveSum(float v) {
#pragma unroll
  for (int o = 32; o > 0; o >>= 1) v += __shfl_down(v, o);
  return v;
}

__global__ __launch_bounds__(1024) void softmax_f16_kernel(
    const f16* __restrict__ lg, float* __restrict__ out) {
  const f16x8* L = (const f16x8*)(lg + (size_t)blockIdx.x * V_DIM);
  float4* p4 = (float4*)(out + (size_t)blockIdx.x * V_DIM);
  const int t = threadIdx.x;
  __shared__ float sred[16];

  float4 v[8];   // chunk j -> float4 2j, 2j+1 (8 logits)
  float m = -1e30f;
#pragma unroll
  for (int j = 0; j < 4; ++j) {
    const int i = j * 1024 + t;        // f16x8 index, < 4000
    if (i < 4000) {
      const f16x8 h = L[i];
      v[2 * j].x     = (float)h[0]; v[2 * j].y     = (float)h[1];
      v[2 * j].z     = (float)h[2]; v[2 * j].w     = (float)h[3];
      v[2 * j + 1].x = (float)h[4]; v[2 * j + 1].y = (float)h[5];
      v[2 * j + 1].z = (float)h[6]; v[2 * j + 1].w = (float)h[7];
      m = fmaxf(m, fmaxf(fmaxf(v[2 * j].x, v[2 * j].y),
                         fmaxf(v[2 * j].z, v[2 * j].w)));
      m = fmaxf(m, fmaxf(fmaxf(v[2 * j + 1].x, v[2 * j + 1].y),
                         fmaxf(v[2 * j + 1].z, v[2 * j + 1].w)));
    }
  }
  m = waveMax(m);
  if ((t & 63) == 0) sred[t >> 6] = m;
  __syncthreads();
  float mb = sred[0];
#pragma unroll
  for (int k = 1; k < 16; ++k) mb = fmaxf(mb, sred[k]);
  __syncthreads();

  float s = 0.f;
#pragma unroll
  for (int j = 0; j < 8; ++j) {
    const int i = (j >> 1) * 1024 + t;
    if (i < 4000) {
      v[j].x = expf(v[j].x - mb);
      v[j].y = expf(v[j].y - mb);
      v[j].z = expf(v[j].z - mb);
      v[j].w = expf(v[j].w - mb);
      s += v[j].x + v[j].y + v[j].z + v[j].w;
    }
  }
  s = waveSum(s);
  if ((t & 63) == 0) sred[t >> 6] = s;
  __syncthreads();
  float sb = sred[0];
#pragma unroll
  for (int k = 1; k < 16; ++k) sb += sred[k];
  const float inv = 1.0f / sb;

#pragma unroll
  for (int j = 0; j < 4; ++j) {
    const int i = j * 1024 + t;
    if (i < 4000) {
      float4 a = v[2 * j], b = v[2 * j + 1];
      a.x *= inv; a.y *= inv; a.z *= inv; a.w *= inv;
      b.x *= inv; b.y *= inv; b.z *= inv; b.w *= inv;
      p4[2 * i] = a;
      p4[2 * i + 1] = b;
    }
  }
}

__global__ __launch_bounds__(1024) void softmax_reg_kernel(
    float* __restrict__ out) {
  float4* p4 = (float4*)(out + (size_t)blockIdx.x * V_DIM);
  const int t = threadIdx.x;
  __shared__ float sred[16];
  float4 v[8];
  float m = -1e30f;
#pragma unroll
  for (int j = 0; j < 8; ++j) {
    const int i = j * 1024 + t;
    if (i < 8000) {
      v[j] = p4[i];
      m = fmaxf(m, fmaxf(fmaxf(v[j].x, v[j].y), fmaxf(v[j].z, v[j].w)));
    }
  }
  m = waveMax(m);
  if ((t & 63) == 0) sred[t >> 6] = m;
  __syncthreads();
  float mb = sred[0];
#pragma unroll
  for (int k = 1; k < 16; ++k) mb = fmaxf(mb, sred[k]);
  __syncthreads();
  float s = 0.f;
#pragma unroll
  for (int j = 0; j < 8; ++j) {
    const int i = j * 1024 + t;
    if (i < 8000) {
      v[j].x = expf(v[j].x - mb);
      v[j].y = expf(v[j].y - mb);
      v[j].z = expf(v[j].z - mb);
      v[j].w = expf(v[j].w - mb);
      s += v[j].x + v[j].y + v[j].z + v[j].w;
    }
  }
  s = waveSum(s);
  if ((t & 63) == 0) sred[t >> 6] = s;
  __syncthreads();
  float sb = sred[0];
#pragma unroll
  for (int k = 1; k < 16; ++k) sb += sred[k];
  const float inv = 1.0f / sb;
#pragma unroll
  for (int j = 0; j < 8; ++j) {
    const int i = j * 1024 + t;
    if (i < 8000) {
      float4 o;
      o.x = v[j].x * inv; o.y = v[j].y * inv;
      o.z = v[j].z * inv; o.w = v[j].w * inv;
      p4[i] = o;
    }
  }
}

// ---------------------------------------------------------------------------
extern "C" void kernel_launch(void* const* d_in, const int* in_sizes, int n_in,
                              void* d_out, int out_size, void* d_ws, size_t ws_size,
                              hipStream_t stream) {
  const float* features = (const float*)d_in[0];
  const int*   captions = (const int*)d_in[1];
  const float* emb      = (const float*)d_in[3];
  const float* w_ih     = (const float*)d_in[4];
  const float* w_hh     = (const float*)d_in[5];
  const float* b_ih     = (const float*)d_in[6];
  const float* b_hh     = (const float*)d_in[7];
  const float* fc_w     = (const float*)d_in[8];
  const float* fc_b     = (const float*)d_in[9];
  float* out = (float*)d_out;

  // ---- d_ws layout ----
  char* ws = (char*)d_ws;
  unsigned* bar = (unsigned*)ws;                 ws += 256;
  f16* hs16 = (f16*)ws;  ws += (size_t)B_DIM * T_DIM * H_DIM * 2;  // 1.31 MB
  f16* w16  = (f16*)ws;  ws += (size_t)V_DIM * H_DIM * 2;          // 32.77 MB
  f16* logits16 = (f16*)ws;  // 81.92 MB, only if ws_size admits
  const size_t ws_need_f16logits =
      256 + (size_t)B_DIM * T_DIM * H_DIM * 2 + (size_t)V_DIM * H_DIM * 2 +
      (size_t)1280 * V_DIM * 2;                  // ~116 MB
  const bool use_f16_logits = ws_size >= ws_need_f16logits;

  // ---- transient scratch in d_out (dead before final output writes) ----
  float* P     = out;                          // [1408][2048] f32, 11.5 MB
  f16*   x16   = (f16*)(out + 3000000);        // [1408][512] f16
  f16*   wih16 = (f16*)(out + 3400000);        // [2048][512] f16
  f16*   whh16 = (f16*)(out + 4000000);        // [2048][512] f16
  float* bsum  = out + 4600000;                // [2048] f32
  f16*   h16a  = (f16*)(out + 4700000);        // [64][512] f16
  f16*   h16b  = (f16*)(out + 4800000);        // [64][512] f16

  hipMemsetAsync(bar, 0, 256, stream);

  gather_x16_kernel<<<1408, 128, 0, stream>>>(features, captions, emb, x16);
  convert_w_kernel<<<1024, 256, 0, stream>>>(w_ih, wih16);
  convert_w_kernel<<<1024, 256, 0, stream>>>(w_hh, whh16);
  convert_w_kernel<<<16000, 256, 0, stream>>>(fc_w, w16);
  bias_sum_kernel<<<8, 256, 0, stream>>>(b_ih, b_hh, bsum);

  // proj: P[1408][2048] = x16 @ wih16^T + bsum
  gemm16_kernel<<<dim3(16, 11), 256, 0, stream>>>(x16, wih16, bsum, P, 2048);

  // all 21 LSTM steps in one persistent kernel
  lstm_persistent<<<NBLK_LSTM, 256, 0, stream>>>(P, whh16, h16a, h16b,
                                                 hs16, bar);

  if (use_f16_logits) {
    gemm16_f16out_kernel<<<dim3(250, 10), 256, 0, stream>>>(hs16, w16, fc_b,
                                                            logits16);
    softmax_f16_kernel<<<1280, 1024, 0, stream>>>(logits16, out);
  } else {
    gemm16_kernel<<<dim3(250, 10), 256, 0, stream>>>(hs16, w16, fc_b, out,
                                                     32000);
    softmax_reg_kernel<<<1280, 1024, 0, stream>>>(out);
  }
}

// Round 8
// 373.662 us; speedup vs baseline: 1.7889x; 1.7889x over previous
//
#include <hip/hip_runtime.h>
#include <cstdint>
#include <cstddef>

#define E_DIM 512
#define H_DIM 512
#define V_DIM 32000
#define B_DIM 64
#define T_DIM 20

typedef _Float16 f16;
typedef _Float16 f16x8 __attribute__((ext_vector_type(8)));
typedef _Float16 f16x4 __attribute__((ext_vector_type(4)));
typedef float    f32x4 __attribute__((ext_vector_type(4)));

__device__ __forceinline__ void async_lds16(void* lds, const void* g) {
  __builtin_amdgcn_global_load_lds(
      (const __attribute__((address_space(1))) uint32_t*)g,
      (__attribute__((address_space(3))) uint32_t*)lds, 16, 0, 0);
}

__device__ __forceinline__ float sigmoidf_(float x) {
  return 1.0f / (1.0f + expf(-x));
}

// ---------------------------------------------------------------------------
// Gather x rows to fp16: x16[m][512], m = b*21+t; rows 1344..1407 zero pad.
// ---------------------------------------------------------------------------
__global__ __launch_bounds__(128) void gather_x16_kernel(
    const float* __restrict__ features, const int* __restrict__ captions,
    const float* __restrict__ emb, f16* __restrict__ x16) {
  const int m = blockIdx.x;
  const int j = threadIdx.x;
  f16x4 r4 = {(f16)0.f, (f16)0.f, (f16)0.f, (f16)0.f};
  if (m < 1344) {
    const int b = m / 21;
    const int t = m % 21;
    const float* src = (t == 0)
        ? features + (size_t)b * E_DIM
        : emb + (size_t)captions[b * T_DIM + (t - 1)] * E_DIM;
    const float4 v = ((const float4*)src)[j];
    r4.x = (f16)v.x; r4.y = (f16)v.y; r4.z = (f16)v.z; r4.w = (f16)v.w;
  }
  ((f16x4*)(x16 + (size_t)m * 512))[j] = r4;
}

__global__ __launch_bounds__(256) void convert_w_kernel(
    const float* __restrict__ w, f16* __restrict__ w16) {
  const int i = blockIdx.x * 256 + threadIdx.x;
  const float4 v = ((const float4*)w)[i];
  f16x4 r;
  r.x = (f16)v.x; r.y = (f16)v.y; r.z = (f16)v.z; r.w = (f16)v.w;
  ((f16x4*)w16)[i] = r;
}

__global__ __launch_bounds__(256) void bias_sum_kernel(
    const float* __restrict__ a, const float* __restrict__ b,
    float* __restrict__ o) {
  const int i = blockIdx.x * 256 + threadIdx.x;
  if (i < 2048) o[i] = a[i] + b[i];
}

// ---------------------------------------------------------------------------
// K=512 fp16 GEMM (B^T form): C = A.Bw^T + bias. 128x128 tile, BK=64,
// 4 waves (2x2), 16x16x32 f16 MFMA, global_load_lds. f32-C variant.
// ---------------------------------------------------------------------------
__global__ __launch_bounds__(256) void gemm16_kernel(
    const f16* __restrict__ A, const f16* __restrict__ Bw,
    const float* __restrict__ bias, float* __restrict__ C, int ldc) {
  __shared__ f16 As[128 * 64];
  __shared__ f16 Bs[128 * 64];
  const int tid = threadIdx.x;
  const int lane = tid & 63;
  const int wid = tid >> 6;
  const int m0 = blockIdx.y * 128;
  const int n0 = blockIdx.x * 128;
  const int wm = (wid >> 1) * 64;
  const int wn = (wid & 1) * 64;

  f32x4 acc[4][4];
#pragma unroll
  for (int i = 0; i < 4; ++i)
#pragma unroll
    for (int j = 0; j < 4; ++j) {
      f32x4 z = {0.f, 0.f, 0.f, 0.f};
      acc[i][j] = z;
    }
  const int lr = lane & 15;
  const int lkb = (lane >> 4) * 8;

  for (int kt = 0; kt < 512; kt += 64) {
#pragma unroll
    for (int i = 0; i < 4; ++i) {
      const int off = i * 4096 + wid * 1024 + lane * 16;
      const int row = off >> 7;
      const int colh = (off & 127) >> 1;
      async_lds16((char*)As + i * 4096 + wid * 1024,
                  A + (size_t)(m0 + row) * 512 + kt + colh);
      async_lds16((char*)Bs + i * 4096 + wid * 1024,
                  Bw + (size_t)(n0 + row) * 512 + kt + colh);
    }
    __syncthreads();
#pragma unroll
    for (int ks = 0; ks < 2; ++ks) {
      f16x8 af[4], bf[4];
#pragma unroll
      for (int mi = 0; mi < 4; ++mi)
        af[mi] = *(const f16x8*)&As[(wm + mi * 16 + lr) * 64 + ks * 32 + lkb];
#pragma unroll
      for (int ni = 0; ni < 4; ++ni)
        bf[ni] = *(const f16x8*)&Bs[(wn + ni * 16 + lr) * 64 + ks * 32 + lkb];
#pragma unroll
      for (int mi = 0; mi < 4; ++mi)
#pragma unroll
        for (int ni = 0; ni < 4; ++ni)
          acc[mi][ni] = __builtin_amdgcn_mfma_f32_16x16x32_f16(
              af[mi], bf[ni], acc[mi][ni], 0, 0, 0);
    }
    __syncthreads();
  }

#pragma unroll
  for (int mi = 0; mi < 4; ++mi) {
    const int mbase = m0 + wm + mi * 16 + (lane >> 4) * 4;
#pragma unroll
    for (int ni = 0; ni < 4; ++ni) {
      const int n = n0 + wn + ni * 16 + lr;
      const float bv = bias[n];
#pragma unroll
      for (int r = 0; r < 4; ++r)
        C[(size_t)(mbase + r) * ldc + n] = acc[mi][ni][r] + bv;
    }
  }
}

// Same GEMM, f16 C output (halves logit-write traffic). ldc fixed 32000.
__global__ __launch_bounds__(256) void gemm16_f16out_kernel(
    const f16* __restrict__ A, const f16* __restrict__ Bw,
    const float* __restrict__ bias, f16* __restrict__ C16) {
  __shared__ f16 As[128 * 64];
  __shared__ f16 Bs[128 * 64];
  const int tid = threadIdx.x;
  const int lane = tid & 63;
  const int wid = tid >> 6;
  const int m0 = blockIdx.y * 128;
  const int n0 = blockIdx.x * 128;
  const int wm = (wid >> 1) * 64;
  const int wn = (wid & 1) * 64;

  f32x4 acc[4][4];
#pragma unroll
  for (int i = 0; i < 4; ++i)
#pragma unroll
    for (int j = 0; j < 4; ++j) {
      f32x4 z = {0.f, 0.f, 0.f, 0.f};
      acc[i][j] = z;
    }
  const int lr = lane & 15;
  const int lkb = (lane >> 4) * 8;

  for (int kt = 0; kt < 512; kt += 64) {
#pragma unroll
    for (int i = 0; i < 4; ++i) {
      const int off = i * 4096 + wid * 1024 + lane * 16;
      const int row = off >> 7;
      const int colh = (off & 127) >> 1;
      async_lds16((char*)As + i * 4096 + wid * 1024,
                  A + (size_t)(m0 + row) * 512 + kt + colh);
      async_lds16((char*)Bs + i * 4096 + wid * 1024,
                  Bw + (size_t)(n0 + row) * 512 + kt + colh);
    }
    __syncthreads();
#pragma unroll
    for (int ks = 0; ks < 2; ++ks) {
      f16x8 af[4], bf[4];
#pragma unroll
      for (int mi = 0; mi < 4; ++mi)
        af[mi] = *(const f16x8*)&As[(wm + mi * 16 + lr) * 64 + ks * 32 + lkb];
#pragma unroll
      for (int ni = 0; ni < 4; ++ni)
        bf[ni] = *(const f16x8*)&Bs[(wn + ni * 16 + lr) * 64 + ks * 32 + lkb];
#pragma unroll
      for (int mi = 0; mi < 4; ++mi)
#pragma unroll
        for (int ni = 0; ni < 4; ++ni)
          acc[mi][ni] = __builtin_amdgcn_mfma_f32_16x16x32_f16(
              af[mi], bf[ni], acc[mi][ni], 0, 0, 0);
    }
    __syncthreads();
  }

#pragma unroll
  for (int mi = 0; mi < 4; ++mi) {
    const int mbase = m0 + wm + mi * 16 + (lane >> 4) * 4;
#pragma unroll
    for (int ni = 0; ni < 4; ++ni) {
      const int n = n0 + wn + ni * 16 + lr;
      const float bv = bias[n];
#pragma unroll
      for (int r = 0; r < 4; ++r)
        C16[(size_t)(mbase + r) * 32000 + n] = (f16)(acc[mi][ni][r] + bv);
    }
  }
}

// ---------------------------------------------------------------------------
// One LSTM step, ZERO LDS / ZERO barriers: A-frags (h rows) and B-frags
// (w_hh rows) loaded directly global->VGPR (all L2-hot: h=64KB, w=16KB/blk).
// grid 128 x 256. block -> u0=blk*4 units; wave w -> b-rows w*16..+15.
// C/D: gate-row = lane&15, b = w*16 + (lane>>4)*4 + r.
// Gates i,f,g,o at lanes fr, fr^4, fr^8, fr^12 -> shfl_xor gather.
// t==0: h=0 -> skip MFMA entirely (gates = P).
// ---------------------------------------------------------------------------
__global__ __launch_bounds__(256) void lstm_step_direct(
    const float* __restrict__ P, const f16* __restrict__ Whh,
    const f16* __restrict__ h_in, f16* __restrict__ h_out,
    float* __restrict__ c, f16* __restrict__ hs16, int t) {
  const int tid = threadIdx.x;
  const int lane = tid & 63;
  const int w = tid >> 6;
  const int u0 = blockIdx.x * 4;
  const int fr = lane & 15;
  const int fq = lane >> 4;
  const int grow = (fr >> 2) * 512 + u0 + (fr & 3);

  f32x4 acc = {0.f, 0.f, 0.f, 0.f};
  if (t > 0) {
    const f16* arow = h_in + (size_t)(w * 16 + fr) * 512;
    const f16* brow = Whh + (size_t)grow * 512;
    f16x8 a[16], b[16];
#pragma unroll
    for (int kk = 0; kk < 16; ++kk) {
      const int kc = kk * 32 + fq * 8;
      a[kk] = *(const f16x8*)&arow[kc];
      b[kk] = *(const f16x8*)&brow[kc];
    }
#pragma unroll
    for (int kk = 0; kk < 16; ++kk)
      acc = __builtin_amdgcn_mfma_f32_16x16x32_f16(a[kk], b[kk], acc, 0, 0, 0);
  }

  // add P (input projection + biases); P row m = b*21 + t
#pragma unroll
  for (int r = 0; r < 4; ++r) {
    const int b = w * 16 + fq * 4 + r;
    acc[r] += P[((size_t)b * 21 + t) * 2048 + grow];
  }

#pragma unroll
  for (int r = 0; r < 4; ++r) {
    const float x  = acc[r];
    const float xf = __shfl_xor(x, 4);
    const float xg = __shfl_xor(x, 8);
    const float xo = __shfl_xor(x, 12);
    if (fr < 4) {
      const int b = w * 16 + fq * 4 + r;
      const int u = u0 + fr;
      const size_t bu = (size_t)b * 512 + u;
      const float si = sigmoidf_(x);
      const float sf = sigmoidf_(xf);
      const float tg = tanhf(xg);
      const float so = sigmoidf_(xo);
      const float cn = sf * c[bu] + si * tg;
      c[bu] = cn;
      const float hn = so * tanhf(cn);
      h_out[bu] = (f16)hn;
      if (t >= 1)
        hs16[((size_t)b * T_DIM + (t - 1)) * 512 + u] = (f16)hn;
    }
  }
}

// ---------------------------------------------------------------------------
// Softmax over V=32000, row in registers (1024 thr). f16-logit input variant
// and f32 in-place fallback.
// ---------------------------------------------------------------------------
__device__ __forceinline__ float waveMax(float v) {
#pragma unroll
  for (int o = 32; o > 0; o >>= 1) v = fmaxf(v, __shfl_down(v, o));
  return v;
}
__device__ __forceinline__ float waveSum(float v) {
#pragma unroll
  for (int o = 32; o > 0; o >>= 1) v += __shfl_down(v, o);
  return v;
}

__global__ __launch_bounds__(1024) void softmax_f16_kernel(
    const f16* __restrict__ lg, float* __restrict__ out) {
  const f16x8* L = (const f16x8*)(lg + (size_t)blockIdx.x * V_DIM);
  float4* p4 = (float4*)(out + (size_t)blockIdx.x * V_DIM);
  const int t = threadIdx.x;
  __shared__ float sred[16];

  float4 v[8];
  float m = -1e30f;
#pragma unroll
  for (int j = 0; j < 4; ++j) {
    const int i = j * 1024 + t;        // f16x8 index, < 4000
    if (i < 4000) {
      const f16x8 h = L[i];
      v[2 * j].x     = (float)h[0]; v[2 * j].y     = (float)h[1];
      v[2 * j].z     = (float)h[2]; v[2 * j].w     = (float)h[3];
      v[2 * j + 1].x = (float)h[4]; v[2 * j + 1].y = (float)h[5];
      v[2 * j + 1].z = (float)h[6]; v[2 * j + 1].w = (float)h[7];
      m = fmaxf(m, fmaxf(fmaxf(v[2 * j].x, v[2 * j].y),
                         fmaxf(v[2 * j].z, v[2 * j].w)));
      m = fmaxf(m, fmaxf(fmaxf(v[2 * j + 1].x, v[2 * j + 1].y),
                         fmaxf(v[2 * j + 1].z, v[2 * j + 1].w)));
    }
  }
  m = waveMax(m);
  if ((t & 63) == 0) sred[t >> 6] = m;
  __syncthreads();
  float mb = sred[0];
#pragma unroll
  for (int k = 1; k < 16; ++k) mb = fmaxf(mb, sred[k]);
  __syncthreads();

  float s = 0.f;
#pragma unroll
  for (int j = 0; j < 8; ++j) {
    const int i = (j >> 1) * 1024 + t;
    if (i < 4000) {
      v[j].x = expf(v[j].x - mb);
      v[j].y = expf(v[j].y - mb);
      v[j].z = expf(v[j].z - mb);
      v[j].w = expf(v[j].w - mb);
      s += v[j].x + v[j].y + v[j].z + v[j].w;
    }
  }
  s = waveSum(s);
  if ((t & 63) == 0) sred[t >> 6] = s;
  __syncthreads();
  float sb = sred[0];
#pragma unroll
  for (int k = 1; k < 16; ++k) sb += sred[k];
  const float inv = 1.0f / sb;

#pragma unroll
  for (int j = 0; j < 4; ++j) {
    const int i = j * 1024 + t;
    if (i < 4000) {
      float4 a = v[2 * j], b = v[2 * j + 1];
      a.x *= inv; a.y *= inv; a.z *= inv; a.w *= inv;
      b.x *= inv; b.y *= inv; b.z *= inv; b.w *= inv;
      p4[2 * i] = a;
      p4[2 * i + 1] = b;
    }
  }
}

__global__ __launch_bounds__(1024) void softmax_reg_kernel(
    float* __restrict__ out) {
  float4* p4 = (float4*)(out + (size_t)blockIdx.x * V_DIM);
  const int t = threadIdx.x;
  __shared__ float sred[16];
  float4 v[8];
  float m = -1e30f;
#pragma unroll
  for (int j = 0; j < 8; ++j) {
    const int i = j * 1024 + t;
    if (i < 8000) {
      v[j] = p4[i];
      m = fmaxf(m, fmaxf(fmaxf(v[j].x, v[j].y), fmaxf(v[j].z, v[j].w)));
    }
  }
  m = waveMax(m);
  if ((t & 63) == 0) sred[t >> 6] = m;
  __syncthreads();
  float mb = sred[0];
#pragma unroll
  for (int k = 1; k < 16; ++k) mb = fmaxf(mb, sred[k]);
  __syncthreads();
  float s = 0.f;
#pragma unroll
  for (int j = 0; j < 8; ++j) {
    const int i = j * 1024 + t;
    if (i < 8000) {
      v[j].x = expf(v[j].x - mb);
      v[j].y = expf(v[j].y - mb);
      v[j].z = expf(v[j].z - mb);
      v[j].w = expf(v[j].w - mb);
      s += v[j].x + v[j].y + v[j].z + v[j].w;
    }
  }
  s = waveSum(s);
  if ((t & 63) == 0) sred[t >> 6] = s;
  __syncthreads();
  float sb = sred[0];
#pragma unroll
  for (int k = 1; k < 16; ++k) sb += sred[k];
  const float inv = 1.0f / sb;
#pragma unroll
  for (int j = 0; j < 8; ++j) {
    const int i = j * 1024 + t;
    if (i < 8000) {
      float4 o;
      o.x = v[j].x * inv; o.y = v[j].y * inv;
      o.z = v[j].z * inv; o.w = v[j].w * inv;
      p4[i] = o;
    }
  }
}

// ---------------------------------------------------------------------------
extern "C" void kernel_launch(void* const* d_in, const int* in_sizes, int n_in,
                              void* d_out, int out_size, void* d_ws, size_t ws_size,
                              hipStream_t stream) {
  const float* features = (const float*)d_in[0];
  const int*   captions = (const int*)d_in[1];
  const float* emb      = (const float*)d_in[3];
  const float* w_ih     = (const float*)d_in[4];
  const float* w_hh     = (const float*)d_in[5];
  const float* b_ih     = (const float*)d_in[6];
  const float* b_hh     = (const float*)d_in[7];
  const float* fc_w     = (const float*)d_in[8];
  const float* fc_b     = (const float*)d_in[9];
  float* out = (float*)d_out;

  // ---- d_ws layout (fixed parts first; logits16 tail is optional) ----
  char* ws = (char*)d_ws;
  float* c    = (float*)ws; ws += (size_t)B_DIM * H_DIM * 4;            // 128 KB
  f16*   h16a = (f16*)ws;   ws += (size_t)B_DIM * H_DIM * 2;            // 64 KB
  f16*   h16b = (f16*)ws;   ws += (size_t)B_DIM * H_DIM * 2;            // 64 KB
  f16*   hs16 = (f16*)ws;   ws += (size_t)B_DIM * T_DIM * H_DIM * 2;    // 1.31 MB
  f16*   w16  = (f16*)ws;   ws += (size_t)V_DIM * H_DIM * 2;            // 32.77 MB
  f16*   logits16 = (f16*)ws;  // 81.92 MB if available
  const size_t ws_need_f16logits =
      ((char*)logits16 - (char*)d_ws) + (size_t)1280 * V_DIM * 2;  // ~116 MB
  const bool use_f16_logits = ws_size >= ws_need_f16logits;

  // ---- transient scratch in d_out (dead before final output writes) ----
  float* P     = out;                          // [1408][2048] f32, 11.5 MB
  f16*   x16   = (f16*)(out + 3000000);        // [1408][512] f16
  f16*   wih16 = (f16*)(out + 3400000);        // [2048][512] f16
  f16*   whh16 = (f16*)(out + 4000000);        // [2048][512] f16
  float* bsum  = out + 4600000;                // [2048] f32

  hipMemsetAsync(c, 0, (size_t)B_DIM * H_DIM * 4, stream);

  gather_x16_kernel<<<1408, 128, 0, stream>>>(features, captions, emb, x16);
  convert_w_kernel<<<1024, 256, 0, stream>>>(w_ih, wih16);
  convert_w_kernel<<<1024, 256, 0, stream>>>(w_hh, whh16);
  convert_w_kernel<<<16000, 256, 0, stream>>>(fc_w, w16);
  bias_sum_kernel<<<8, 256, 0, stream>>>(b_ih, b_hh, bsum);

  // proj: P[1408][2048] = x16 @ wih16^T + bsum
  gemm16_kernel<<<dim3(16, 11), 256, 0, stream>>>(x16, wih16, bsum, P, 2048);

  // 21 LSTM steps, one light launch each (no LDS, no barriers)
  f16* hb[2] = {h16a, h16b};
  for (int t = 0; t <= T_DIM; ++t) {
    lstm_step_direct<<<128, 256, 0, stream>>>(P, whh16, hb[t & 1],
                                              hb[(t + 1) & 1], c, hs16, t);
  }

  if (use_f16_logits) {
    gemm16_f16out_kernel<<<dim3(250, 10), 256, 0, stream>>>(hs16, w16, fc_b,
                                                            logits16);
    softmax_f16_kernel<<<1280, 1024, 0, stream>>>(logits16, out);
  } else {
    gemm16_kernel<<<dim3(250, 10), 256, 0, stream>>>(hs16, w16, fc_b, out,
                                                     32000);
    softmax_reg_kernel<<<1280, 1024, 0, stream>>>(out);
  }
}